// Round 1
// baseline (749.708 us; speedup 1.0000x reference)
//
#include <hip/hip_runtime.h>
#include <math.h>

#define TBN 1024
#define TC  32
#define TP  7
#define TG  8
#define TD  160
#define TW  167
#define TK  3
#define TTH 16
#define CPG 4
#define NEGV -1e9f

typedef float f4 __attribute__((ext_vector_type(4)));

__global__ __launch_bounds__(256, 4)
void patchmix_kernel(const float* __restrict__ left,
                     const float* __restrict__ right,
                     const int*   __restrict__ start_left,
                     const float* __restrict__ f1w,
                     const float* __restrict__ f1b,
                     const float* __restrict__ convw,
                     const float* __restrict__ convb,
                     float* __restrict__ out)
{
    __shared__ float s_left[TC * TP * TP];            // 1568
    __shared__ __align__(16) float s_feat[TD][TG];    // feature [d][g]
    __shared__ float s_h[TD * 9];                     // h, stride 9 (bank-spread)
    __shared__ float s_accP[TD * 9];                  // accum pos -> reused as feat'
    __shared__ float s_accN[TD * 9];                  // accum neg
    __shared__ float s_norm[TD];
    __shared__ float s_agg[TD];
    __shared__ float s_f1w[TG * TG];
    __shared__ float s_f1b[TG];
    __shared__ float s_cw[TG * 3];
    __shared__ float s_cb;
    __shared__ int   s_idx[TD][TK];
    __shared__ int   s_near[TD][TK];
    __shared__ int   s_degP[TD];
    __shared__ int   s_degN[TD];

    const int bn = blockIdx.x;
    const int t  = threadIdx.x;
    const int start = start_left[bn];

    // ---------- phase 0: stage left patch + weights ----------
    {
        const float* lsrc = left + bn * (TC * TP * TP);
        for (int i = t; i < TC * TP * TP; i += 256) s_left[i] = lsrc[i];
        if (t < 64)        s_f1w[t]      = f1w[t];
        else if (t < 72)   s_f1b[t - 64] = f1b[t - 64];
        else if (t < 96)   s_cw[t - 72]  = convw[t - 72];
        else if (t == 96)  s_cb          = convb[0];
    }
    __syncthreads();

    // ---------- phase 1: group-wise correlation cost volume ----------
    // tasks: 8 groups x 40 d-quads. Each task computes vol[g][4dq..4dq+3]
    // via a 10-float sliding register window per (c,y) row.
    for (int task = t; task < 320; task += 256) {
        const int g  = task / 40;
        const int dq = task - g * 40;
        const int d0 = dq * 4;
        float a0 = 0.f, a1 = 0.f, a2 = 0.f, a3 = 0.f;
        if (d0 <= start) {
            const int col0 = start - d0 - 3;       // >= -3
            const float* rbase = right + ((bn * TC + g * CPG) * TP) * TW;
            const float* lbase = s_left + g * CPG * TP * TP;
            for (int cy = 0; cy < CPG * TP; ++cy) {
                const float* rp = rbase + cy * TW + col0;
                float r0, r1, r2, r3, r4, r5, r6, r7, r8, r9;
                if (col0 >= 0) {
                    float tmp[10];
                    __builtin_memcpy(tmp, rp, 40);   // unaligned-safe vector load
                    r0 = tmp[0]; r1 = tmp[1]; r2 = tmp[2]; r3 = tmp[3]; r4 = tmp[4];
                    r5 = tmp[5]; r6 = tmp[6]; r7 = tmp[7]; r8 = tmp[8]; r9 = tmp[9];
                } else {
                    // only r0..r2 can be out of range (col0 in [-3,-1]); those
                    // feed only invalid d which get masked at the write.
                    r0 = (col0 + 0 >= 0) ? rp[0] : 0.f;
                    r1 = (col0 + 1 >= 0) ? rp[1] : 0.f;
                    r2 = (col0 + 2 >= 0) ? rp[2] : 0.f;
                    r3 = rp[3]; r4 = rp[4]; r5 = rp[5];
                    r6 = rp[6]; r7 = rp[7]; r8 = rp[8]; r9 = rp[9];
                }
                const float* lp = lbase + cy * TP;
                const float l0 = lp[0], l1 = lp[1], l2 = lp[2], l3 = lp[3],
                            l4 = lp[4], l5 = lp[5], l6 = lp[6];
#define FMAROW(acc, rA, rB, rC, rD, rE, rF, rG) \
                acc = fmaf(l0, rA, acc); acc = fmaf(l1, rB, acc); \
                acc = fmaf(l2, rC, acc); acc = fmaf(l3, rD, acc); \
                acc = fmaf(l4, rE, acc); acc = fmaf(l5, rF, acc); \
                acc = fmaf(l6, rG, acc);
                FMAROW(a0, r3, r4, r5, r6, r7, r8, r9)
                FMAROW(a1, r2, r3, r4, r5, r6, r7, r8)
                FMAROW(a2, r1, r2, r3, r4, r5, r6, r7)
                FMAROW(a3, r0, r1, r2, r3, r4, r5, r6)
#undef FMAROW
            }
        }
        s_feat[d0 + 0][g] = (d0 + 0 <= start) ? a0 / 196.0f : 0.f;
        s_feat[d0 + 1][g] = (d0 + 1 <= start) ? a1 / 196.0f : 0.f;
        s_feat[d0 + 2][g] = (d0 + 2 <= start) ? a2 / 196.0f : 0.f;
        s_feat[d0 + 3][g] = (d0 + 3 <= start) ? a3 / 196.0f : 0.f;
    }
    __syncthreads();

    // ---------- phase 1b: row norms ----------
    if (t < TD) {
        float s = 0.f;
#pragma unroll
        for (int g = 0; g < TG; ++g) { float v = s_feat[t][g]; s = fmaf(v, v, s); }
        s_norm[t] = s;
    }
    __syncthreads();

    // ---------- phase 2: kNN top-3 (threads<160); zero accums (threads>=160) ----------
    if (t < TD) {
        const f4 fa = ((const f4*)s_feat[t])[0];
        const f4 fb = ((const f4*)s_feat[t])[1];
        const float ni = s_norm[t];
        float v0 = 3e38f, v1 = 3e38f, v2 = 3e38f;
        int   i0 = -1,    i1 = -1,    i2 = -1;
        for (int j = 0; j < TD; ++j) {
            const f4 ga = ((const f4*)s_feat[j])[0];
            const f4 gb = ((const f4*)s_feat[j])[1];
            float dot = fa.x * ga.x + fa.y * ga.y + fa.z * ga.z + fa.w * ga.w
                      + fb.x * gb.x + fb.y * gb.y + fb.z * gb.z + fb.w * gb.w;
            // zero-feature rows give exactly 0 here (ties -> lower index, as in
            // jax.lax.top_k, reproduced by strict < with ascending j)
            float dist = ni + s_norm[j] - 2.f * dot;
            if (dist < v2) {
                v2 = dist; i2 = j;
                if (v2 < v1) {
                    float tv = v1; v1 = v2; v2 = tv; int ti = i1; i1 = i2; i2 = ti;
                    if (v1 < v0) {
                        tv = v0; v0 = v1; v1 = tv; ti = i0; i0 = i1; i1 = ti;
                    }
                }
            }
        }
        s_idx[t][0] = i0; s_idx[t][1] = i1; s_idx[t][2] = i2;
        int dk0 = i0 - t, dk1 = i1 - t, dk2 = i2 - t;
        s_near[t][0] = (dk0 < TTH && dk0 > -TTH);
        s_near[t][1] = (dk1 < TTH && dk1 > -TTH);
        s_near[t][2] = (dk2 < TTH && dk2 > -TTH);
    } else {
        for (int i = t - TD; i < TD * 9; i += 96) { s_accP[i] = 0.f; s_accN[i] = 0.f; }
        for (int i = t - TD; i < TD;     i += 96) { s_degP[i] = 0;   s_degN[i] = 0;   }
    }
    __syncthreads();

    // ---------- phase 3: h = leaky_relu(feature @ f1w^T + f1b) ----------
    for (int task = t; task < TD * TG; task += 256) {
        const int d = task >> 3, go = task & 7;
        float s = s_f1b[go];
#pragma unroll
        for (int gi = 0; gi < TG; ++gi) s = fmaf(s_feat[d][gi], s_f1w[go * TG + gi], s);
        s_h[d * 9 + go] = (s >= 0.f) ? s : 0.01f * s;
    }
    __syncthreads();

    // ---------- phase 4/5: E = mean(h over near/far kNN), scatter to targets ----------
    if (t < TD) {
        const int jj[3] = { s_idx[t][0], s_idx[t][1], s_idx[t][2] };
        const int nr[3] = { s_near[t][0], s_near[t][1], s_near[t][2] };
        float ep[TG] = {0, 0, 0, 0, 0, 0, 0, 0};
        float en[TG] = {0, 0, 0, 0, 0, 0, 0, 0};
        int cp = 0, cn = 0;
#pragma unroll
        for (int k = 0; k < TK; ++k) {
            const float* hp = &s_h[jj[k] * 9];
            if (nr[k]) { cp++;
#pragma unroll
                for (int g = 0; g < TG; ++g) ep[g] += hp[g];
            } else { cn++;
#pragma unroll
                for (int g = 0; g < TG; ++g) en[g] += hp[g];
            }
        }
        if (cp) {
#pragma unroll
            for (int g = 0; g < TG; ++g) ep[g] /= (float)cp;
        }
        if (cn) {
#pragma unroll
            for (int g = 0; g < TG; ++g) en[g] /= (float)cn;
        }
#pragma unroll
        for (int k = 0; k < TK; ++k) {
            if (nr[k]) {
                atomicAdd(&s_degP[jj[k]], 1);
#pragma unroll
                for (int g = 0; g < TG; ++g) atomicAdd(&s_accP[jj[k] * 9 + g], ep[g]);
            } else {
                atomicAdd(&s_degN[jj[k]], 1);
#pragma unroll
                for (int g = 0; g < TG; ++g) atomicAdd(&s_accN[jj[k] * 9 + g], en[g]);
            }
        }
    }
    __syncthreads();

    // ---------- phase 5b: feat' = feature + 0.1*x1 - 0.1*x2 (in-place in s_accP) ----------
    if (t < TD) {
        const int dp = s_degP[t], dn = s_degN[t];
#pragma unroll
        for (int g = 0; g < TG; ++g) {
            float x1 = dp ? s_accP[t * 9 + g] / (float)dp : 0.f;
            float x2 = dn ? s_accN[t * 9 + g] / (float)dn : 0.f;
            s_accP[t * 9 + g] = s_feat[t][g] + 0.1f * x1 - 0.1f * x2;
        }
    }
    __syncthreads();

    // ---------- phase 6: conv1d(k=3,pad=1) over D + mask ----------
    if (t < TD) {
        float msum = 0.f;
#pragma unroll
        for (int g = 0; g < TG; ++g) msum += s_feat[t][g];
        float a = s_cb;
#pragma unroll
        for (int kw = 0; kw < 3; ++kw) {
            const int dd = t + kw - 1;
            if (dd >= 0 && dd < TD) {
#pragma unroll
                for (int g = 0; g < TG; ++g)
                    a = fmaf(s_accP[dd * 9 + g], s_cw[g * 3 + kw], a);
            }
        }
        s_agg[t] = (msum == 0.f) ? NEGV : a;
    }
    __syncthreads();

    // ---------- phase 7: softmax + disparity regression (wave 0) ----------
    if (t < 64) {
        float m = -3e38f;
        for (int d = t; d < TD; d += 64) m = fmaxf(m, s_agg[d]);
#pragma unroll
        for (int off = 32; off; off >>= 1) m = fmaxf(m, __shfl_xor(m, off, 64));
        float se = 0.f, sd = 0.f;
        for (int d = t; d < TD; d += 64) {
            float e = expf(s_agg[d] - m);
            se += e;
            sd = fmaf(e, (float)d, sd);
        }
#pragma unroll
        for (int off = 32; off; off >>= 1) {
            se += __shfl_xor(se, off, 64);
            sd += __shfl_xor(sd, off, 64);
        }
        if (t == 0) out[bn] = sd / se;
    }
}

extern "C" void kernel_launch(void* const* d_in, const int* in_sizes, int n_in,
                              void* d_out, int out_size, void* d_ws, size_t ws_size,
                              hipStream_t stream) {
    const float* left   = (const float*)d_in[0];
    const float* right  = (const float*)d_in[1];
    const int*   start  = (const int*)d_in[2];
    const float* f1w    = (const float*)d_in[3];
    const float* f1b    = (const float*)d_in[4];
    const float* convw  = (const float*)d_in[5];
    const float* convb  = (const float*)d_in[6];
    float* out = (float*)d_out;
    patchmix_kernel<<<TBN, 256, 0, stream>>>(left, right, start, f1w, f1b,
                                             convw, convb, out);
}

// Round 2
// 294.640 us; speedup vs baseline: 2.5445x; 2.5445x over previous
//
#include <hip/hip_runtime.h>
#include <math.h>

#define TBN 1024
#define TC  32
#define TP  7
#define TG  8
#define TD  160
#define TW  167
#define TK  3
#define TTH 16
#define CPG 4
#define NEGV -1e9f

typedef float f4 __attribute__((ext_vector_type(4)));

__global__ __launch_bounds__(256, 4)
void patchmix_kernel(const float* __restrict__ left,
                     const float* __restrict__ right,
                     const int*   __restrict__ start_left,
                     const float* __restrict__ f1w,
                     const float* __restrict__ f1b,
                     const float* __restrict__ convw,
                     const float* __restrict__ convb,
                     float* __restrict__ out)
{
    __shared__ float s_left[TC * TP * TP];            // 1568
    __shared__ __align__(16) float s_feat[TD][TG];    // feature [d][g]
    __shared__ float s_h[TD * 9];                     // h, stride 9 (bank-spread)
    __shared__ float s_accP[TD * 9];                  // accum pos -> reused as feat'
    __shared__ float s_accN[TD * 9];                  // accum neg
    __shared__ float s_norm[TD];
    __shared__ float s_agg[TD];
    __shared__ float s_f1w[TG * TG];
    __shared__ float s_f1b[TG];
    __shared__ float s_cw[TG * 3];
    __shared__ float s_cb;
    __shared__ int   s_idx[TD][TK];
    __shared__ int   s_near[TD][TK];
    __shared__ int   s_degP[TD];
    __shared__ int   s_degN[TD];

    const int bn = blockIdx.x;
    const int t  = threadIdx.x;
    const int start = start_left[bn];

    // ---------- phase 0: stage left patch + weights ----------
    {
        const float* lsrc = left + bn * (TC * TP * TP);
        for (int i = t; i < TC * TP * TP; i += 256) s_left[i] = lsrc[i];
        if (t < 64)        s_f1w[t]      = f1w[t];
        else if (t < 72)   s_f1b[t - 64] = f1b[t - 64];
        else if (t < 96)   s_cw[t - 72]  = convw[t - 72];
        else if (t == 96)  s_cb          = convb[0];
    }
    __syncthreads();

    // ---------- phase 1: group-wise correlation cost volume ----------
    // tasks: 8 groups x 40 d-quads. Each task computes vol[g][4dq..4dq+3]
    // via a 10-float sliding register window per (c,y) row.
    // NOTE: direct scalar register loads (NO memcpy/stack — R0's memcpy put
    // tmp[10] in scratch: 367 MB of HBM write traffic, WRITE_SIZE counter).
    for (int task = t; task < 320; task += 256) {
        const int g  = task / 40;
        const int dq = task - g * 40;
        const int d0 = dq * 4;
        float a0 = 0.f, a1 = 0.f, a2 = 0.f, a3 = 0.f;
        if (d0 <= start) {
            const int col0 = start - d0 - 3;       // >= -3
            const float* rp = right + ((bn * TC + g * CPG) * TP) * TW + col0;
            const float* lp = s_left + g * CPG * TP * TP;
            for (int cy = 0; cy < CPG * TP; ++cy) {
                float r0, r1, r2, r3, r4, r5, r6, r7, r8, r9;
                if (col0 >= 0) {
                    r0 = rp[0]; r1 = rp[1]; r2 = rp[2]; r3 = rp[3]; r4 = rp[4];
                    r5 = rp[5]; r6 = rp[6]; r7 = rp[7]; r8 = rp[8]; r9 = rp[9];
                } else {
                    // only r0..r2 can be OOB (col0 in [-3,-1]); they feed only
                    // invalid d which get masked at the write.
                    r0 = (col0 + 0 >= 0) ? rp[0] : 0.f;
                    r1 = (col0 + 1 >= 0) ? rp[1] : 0.f;
                    r2 = (col0 + 2 >= 0) ? rp[2] : 0.f;
                    r3 = rp[3]; r4 = rp[4]; r5 = rp[5];
                    r6 = rp[6]; r7 = rp[7]; r8 = rp[8]; r9 = rp[9];
                }
                const float l0 = lp[0], l1 = lp[1], l2 = lp[2], l3 = lp[3],
                            l4 = lp[4], l5 = lp[5], l6 = lp[6];
#define FMAROW(acc, rA, rB, rC, rD, rE, rF, rG) \
                acc = fmaf(l0, rA, acc); acc = fmaf(l1, rB, acc); \
                acc = fmaf(l2, rC, acc); acc = fmaf(l3, rD, acc); \
                acc = fmaf(l4, rE, acc); acc = fmaf(l5, rF, acc); \
                acc = fmaf(l6, rG, acc);
                FMAROW(a0, r3, r4, r5, r6, r7, r8, r9)
                FMAROW(a1, r2, r3, r4, r5, r6, r7, r8)
                FMAROW(a2, r1, r2, r3, r4, r5, r6, r7)
                FMAROW(a3, r0, r1, r2, r3, r4, r5, r6)
#undef FMAROW
                rp += TW;
                lp += TP;
            }
        }
        s_feat[d0 + 0][g] = (d0 + 0 <= start) ? a0 / 196.0f : 0.f;
        s_feat[d0 + 1][g] = (d0 + 1 <= start) ? a1 / 196.0f : 0.f;
        s_feat[d0 + 2][g] = (d0 + 2 <= start) ? a2 / 196.0f : 0.f;
        s_feat[d0 + 3][g] = (d0 + 3 <= start) ? a3 / 196.0f : 0.f;
    }
    __syncthreads();

    // ---------- phase 1b: row norms ----------
    if (t < TD) {
        float s = 0.f;
#pragma unroll
        for (int g = 0; g < TG; ++g) { float v = s_feat[t][g]; s = fmaf(v, v, s); }
        s_norm[t] = s;
    }
    __syncthreads();

    // ---------- phase 2: kNN top-3 (threads<160); zero accums (threads>=160) ----------
    if (t < TD) {
        const f4 fa = ((const f4*)s_feat[t])[0];
        const f4 fb = ((const f4*)s_feat[t])[1];
        const float ni = s_norm[t];
        float v0 = 3e38f, v1 = 3e38f, v2 = 3e38f;
        int   i0 = -1,    i1 = -1,    i2 = -1;
        for (int j = 0; j < TD; ++j) {
            const f4 ga = ((const f4*)s_feat[j])[0];
            const f4 gb = ((const f4*)s_feat[j])[1];
            float dot = fa.x * ga.x + fa.y * ga.y + fa.z * ga.z + fa.w * ga.w
                      + fb.x * gb.x + fb.y * gb.y + fb.z * gb.z + fb.w * gb.w;
            // zero-feature rows give exactly 0 here (ties -> lower index, as in
            // jax.lax.top_k, reproduced by strict < with ascending j)
            float dist = ni + s_norm[j] - 2.f * dot;
            if (dist < v2) {
                v2 = dist; i2 = j;
                if (v2 < v1) {
                    float tv = v1; v1 = v2; v2 = tv; int ti = i1; i1 = i2; i2 = ti;
                    if (v1 < v0) {
                        tv = v0; v0 = v1; v1 = tv; ti = i0; i0 = i1; i1 = ti;
                    }
                }
            }
        }
        s_idx[t][0] = i0; s_idx[t][1] = i1; s_idx[t][2] = i2;
        int dk0 = i0 - t, dk1 = i1 - t, dk2 = i2 - t;
        s_near[t][0] = (dk0 < TTH && dk0 > -TTH);
        s_near[t][1] = (dk1 < TTH && dk1 > -TTH);
        s_near[t][2] = (dk2 < TTH && dk2 > -TTH);
    } else {
        for (int i = t - TD; i < TD * 9; i += 96) { s_accP[i] = 0.f; s_accN[i] = 0.f; }
        for (int i = t - TD; i < TD;     i += 96) { s_degP[i] = 0;   s_degN[i] = 0;   }
    }
    __syncthreads();

    // ---------- phase 3: h = leaky_relu(feature @ f1w^T + f1b) ----------
    for (int task = t; task < TD * TG; task += 256) {
        const int d = task >> 3, go = task & 7;
        float s = s_f1b[go];
#pragma unroll
        for (int gi = 0; gi < TG; ++gi) s = fmaf(s_feat[d][gi], s_f1w[go * TG + gi], s);
        s_h[d * 9 + go] = (s >= 0.f) ? s : 0.01f * s;
    }
    __syncthreads();

    // ---------- phase 4/5: E = mean(h over near/far kNN), scatter to targets ----------
    if (t < TD) {
        const int jj[3] = { s_idx[t][0], s_idx[t][1], s_idx[t][2] };
        const int nr[3] = { s_near[t][0], s_near[t][1], s_near[t][2] };
        float ep[TG] = {0, 0, 0, 0, 0, 0, 0, 0};
        float en[TG] = {0, 0, 0, 0, 0, 0, 0, 0};
        int cp = 0, cn = 0;
#pragma unroll
        for (int k = 0; k < TK; ++k) {
            const float* hp = &s_h[jj[k] * 9];
            if (nr[k]) { cp++;
#pragma unroll
                for (int g = 0; g < TG; ++g) ep[g] += hp[g];
            } else { cn++;
#pragma unroll
                for (int g = 0; g < TG; ++g) en[g] += hp[g];
            }
        }
        if (cp) {
#pragma unroll
            for (int g = 0; g < TG; ++g) ep[g] /= (float)cp;
        }
        if (cn) {
#pragma unroll
            for (int g = 0; g < TG; ++g) en[g] /= (float)cn;
        }
#pragma unroll
        for (int k = 0; k < TK; ++k) {
            if (nr[k]) {
                atomicAdd(&s_degP[jj[k]], 1);
#pragma unroll
                for (int g = 0; g < TG; ++g) atomicAdd(&s_accP[jj[k] * 9 + g], ep[g]);
            } else {
                atomicAdd(&s_degN[jj[k]], 1);
#pragma unroll
                for (int g = 0; g < TG; ++g) atomicAdd(&s_accN[jj[k] * 9 + g], en[g]);
            }
        }
    }
    __syncthreads();

    // ---------- phase 5b: feat' = feature + 0.1*x1 - 0.1*x2 (in-place in s_accP) ----------
    if (t < TD) {
        const int dp = s_degP[t], dn = s_degN[t];
#pragma unroll
        for (int g = 0; g < TG; ++g) {
            float x1 = dp ? s_accP[t * 9 + g] / (float)dp : 0.f;
            float x2 = dn ? s_accN[t * 9 + g] / (float)dn : 0.f;
            s_accP[t * 9 + g] = s_feat[t][g] + 0.1f * x1 - 0.1f * x2;
        }
    }
    __syncthreads();

    // ---------- phase 6: conv1d(k=3,pad=1) over D + mask ----------
    if (t < TD) {
        float msum = 0.f;
#pragma unroll
        for (int g = 0; g < TG; ++g) msum += s_feat[t][g];
        float a = s_cb;
#pragma unroll
        for (int kw = 0; kw < 3; ++kw) {
            const int dd = t + kw - 1;
            if (dd >= 0 && dd < TD) {
#pragma unroll
                for (int g = 0; g < TG; ++g)
                    a = fmaf(s_accP[dd * 9 + g], s_cw[g * 3 + kw], a);
            }
        }
        s_agg[t] = (msum == 0.f) ? NEGV : a;
    }
    __syncthreads();

    // ---------- phase 7: softmax + disparity regression (wave 0) ----------
    if (t < 64) {
        float m = -3e38f;
        for (int d = t; d < TD; d += 64) m = fmaxf(m, s_agg[d]);
#pragma unroll
        for (int off = 32; off; off >>= 1) m = fmaxf(m, __shfl_xor(m, off, 64));
        float se = 0.f, sd = 0.f;
        for (int d = t; d < TD; d += 64) {
            float e = expf(s_agg[d] - m);
            se += e;
            sd = fmaf(e, (float)d, sd);
        }
#pragma unroll
        for (int off = 32; off; off >>= 1) {
            se += __shfl_xor(se, off, 64);
            sd += __shfl_xor(sd, off, 64);
        }
        if (t == 0) out[bn] = sd / se;
    }
}

extern "C" void kernel_launch(void* const* d_in, const int* in_sizes, int n_in,
                              void* d_out, int out_size, void* d_ws, size_t ws_size,
                              hipStream_t stream) {
    const float* left   = (const float*)d_in[0];
    const float* right  = (const float*)d_in[1];
    const int*   start  = (const int*)d_in[2];
    const float* f1w    = (const float*)d_in[3];
    const float* f1b    = (const float*)d_in[4];
    const float* convw  = (const float*)d_in[5];
    const float* convb  = (const float*)d_in[6];
    float* out = (float*)d_out;
    patchmix_kernel<<<TBN, 256, 0, stream>>>(left, right, start, f1w, f1b,
                                             convw, convb, out);
}

// Round 3
// 289.230 us; speedup vs baseline: 2.5921x; 1.0187x over previous
//
#include <hip/hip_runtime.h>
#include <math.h>

#define TBN 1024
#define TC  32
#define TP  7
#define TG  8
#define TD  160
#define TW  167
#define TK  3
#define TTH 16
#define CPG 4
#define NEGV -1e9f

typedef float f4 __attribute__((ext_vector_type(4)));

__global__ __launch_bounds__(256, 4)
void patchmix_kernel(const float* __restrict__ left,
                     const float* __restrict__ right,
                     const int*   __restrict__ start_left,
                     const float* __restrict__ f1w,
                     const float* __restrict__ f1b,
                     const float* __restrict__ convw,
                     const float* __restrict__ convb,
                     float* __restrict__ out)
{
    // s_pool: phase 0-1 = padded left patch [28*8 floats per g, 8 g] (1792)
    //         phase 2+  = accP (1440) + accN (1440)   [disjoint lifetimes]
    __shared__ __align__(16) float s_pool[2880];
    __shared__ __align__(16) float s_feat[TD][TG];    // feature [d][g]
    __shared__ float s_h[TD * 9];                     // h, stride 9
    __shared__ float s_norm[TD];
    __shared__ float s_agg[TD];
    __shared__ float s_f1w[TG * TG];
    __shared__ float s_f1b[TG];
    __shared__ float s_cw[TG * 3];
    __shared__ float s_cb;
    __shared__ int   s_idx[TD][TK];
    __shared__ int   s_near[TD][TK];
    __shared__ int   s_degP[TD];
    __shared__ int   s_degN[TD];

    float* const s_lp   = s_pool;          // [g*28 + row][8] padded left
    float* const s_accP = s_pool;          // 1440, zeroed in phase 2
    float* const s_accN = s_pool + 1440;   // 1440

    const int bn = blockIdx.x;
    const int t  = threadIdx.x;
    const int start = start_left[bn];

    // ---------- phase 0: stage left patch (8-strided rows) + weights ----------
    {
        const float* lsrc = left + bn * (TC * TP * TP);
        for (int i = t; i < TC * TP * TP; i += 256) {
            const int cy = i / 7;          // global row index (c*7+y)
            const int x  = i - cy * 7;
            s_lp[cy * 8 + x] = lsrc[i];
        }
        if (t < 64)        s_f1w[t]      = f1w[t];
        else if (t < 72)   s_f1b[t - 64] = f1b[t - 64];
        else if (t < 96)   s_cw[t - 72]  = convw[t - 72];
        else if (t == 96)  s_cb          = convb[0];
    }
    __syncthreads();

    // ---------- phase 1: group-wise correlation cost volume ----------
    // Exactly 256 tasks: g = t>>5, 5 disparities per task (d0 = (t&31)*5).
    // 11-float sliding register window per row, 2-row software pipeline.
    // Boundary: clamped load offsets (garbage values only feed accs that are
    // masked at the write — all r feeding VALID accs are provably in-bounds).
    {
        const int g  = t >> 5;
        const int d0 = (t & 31) * 5;
        float a0 = 0.f, a1 = 0.f, a2 = 0.f, a3 = 0.f, a4 = 0.f;
        if (d0 <= start) {
            const int col0 = start - d0 - 4;        // >= -4
            const float* rp = right + ((bn * TC + g * CPG) * TP) * TW + col0;
            const float* lq = s_lp + g * (CPG * TP) * 8;
            const int o0 = (col0 >=  0) ? 0 : 4;
            const int o1 = (col0 >= -1) ? 1 : 4;
            const int o2 = (col0 >= -2) ? 2 : 4;
            const int o3 = (col0 >= -3) ? 3 : 4;
            float w0,w1,w2,w3,w4,w5,w6,w7,w8,w9,w10;
            float x0,x1,x2,x3,x4,x5,x6,x7,x8,x9,x10;
#define LOADW(b0,b1,b2,b3,b4,b5,b6,b7,b8,b9,b10,p) \
            b0=(p)[o0]; b1=(p)[o1]; b2=(p)[o2]; b3=(p)[o3]; b4=(p)[4]; \
            b5=(p)[5]; b6=(p)[6]; b7=(p)[7]; b8=(p)[8]; b9=(p)[9]; b10=(p)[10];
#define FMA5(la,lb,r0,r1,r2,r3,r4,r5,r6,r7,r8,r9,r10) \
            a0=fmaf(la.x,r4,a0);  a0=fmaf(la.y,r5,a0);  a0=fmaf(la.z,r6,a0); \
            a0=fmaf(la.w,r7,a0);  a0=fmaf(lb.x,r8,a0);  a0=fmaf(lb.y,r9,a0); \
            a0=fmaf(lb.z,r10,a0); \
            a1=fmaf(la.x,r3,a1);  a1=fmaf(la.y,r4,a1);  a1=fmaf(la.z,r5,a1); \
            a1=fmaf(la.w,r6,a1);  a1=fmaf(lb.x,r7,a1);  a1=fmaf(lb.y,r8,a1); \
            a1=fmaf(lb.z,r9,a1); \
            a2=fmaf(la.x,r2,a2);  a2=fmaf(la.y,r3,a2);  a2=fmaf(la.z,r4,a2); \
            a2=fmaf(la.w,r5,a2);  a2=fmaf(lb.x,r6,a2);  a2=fmaf(lb.y,r7,a2); \
            a2=fmaf(lb.z,r8,a2); \
            a3=fmaf(la.x,r1,a3);  a3=fmaf(la.y,r2,a3);  a3=fmaf(la.z,r3,a3); \
            a3=fmaf(la.w,r4,a3);  a3=fmaf(lb.x,r5,a3);  a3=fmaf(lb.y,r6,a3); \
            a3=fmaf(lb.z,r7,a3); \
            a4=fmaf(la.x,r0,a4);  a4=fmaf(la.y,r1,a4);  a4=fmaf(la.z,r2,a4); \
            a4=fmaf(la.w,r3,a4);  a4=fmaf(lb.x,r4,a4);  a4=fmaf(lb.y,r5,a4); \
            a4=fmaf(lb.z,r6,a4);

            LOADW(w0,w1,w2,w3,w4,w5,w6,w7,w8,w9,w10, rp)        // row 0
            for (int h = 0; h < 14; ++h) {
                const f4 la0 = *(const f4*)(lq);        // left row 2h
                const f4 lb0 = *(const f4*)(lq + 4);
                const f4 la1 = *(const f4*)(lq + 8);    // left row 2h+1
                const f4 lb1 = *(const f4*)(lq + 12);
                LOADW(x0,x1,x2,x3,x4,x5,x6,x7,x8,x9,x10, rp + TW)  // row 2h+1
                FMA5(la0, lb0, w0,w1,w2,w3,w4,w5,w6,w7,w8,w9,w10)  // row 2h
                rp += 2 * TW;
                if (h < 13) {
                    LOADW(w0,w1,w2,w3,w4,w5,w6,w7,w8,w9,w10, rp)   // row 2h+2
                }
                FMA5(la1, lb1, x0,x1,x2,x3,x4,x5,x6,x7,x8,x9,x10)  // row 2h+1
                lq += 16;
            }
#undef LOADW
#undef FMA5
        }
        s_feat[d0 + 0][g] = (d0 + 0 <= start) ? a0 / 196.0f : 0.f;
        s_feat[d0 + 1][g] = (d0 + 1 <= start) ? a1 / 196.0f : 0.f;
        s_feat[d0 + 2][g] = (d0 + 2 <= start) ? a2 / 196.0f : 0.f;
        s_feat[d0 + 3][g] = (d0 + 3 <= start) ? a3 / 196.0f : 0.f;
        s_feat[d0 + 4][g] = (d0 + 4 <= start) ? a4 / 196.0f : 0.f;
    }
    __syncthreads();

    // ---------- phase 1b: row norms ----------
    if (t < TD) {
        float s = 0.f;
#pragma unroll
        for (int g = 0; g < TG; ++g) { float v = s_feat[t][g]; s = fmaf(v, v, s); }
        s_norm[t] = s;
    }
    __syncthreads();

    // ---------- phase 2: kNN top-3 (t<160); zero accums (t>=160) ----------
    if (t < TD) {
        const f4 fa = ((const f4*)s_feat[t])[0];
        const f4 fb = ((const f4*)s_feat[t])[1];
        const float ni = s_norm[t];
        float v0 = 3e38f, v1 = 3e38f, v2 = 3e38f;
        int   i0 = -1,    i1 = -1,    i2 = -1;
        for (int j = 0; j < TD; ++j) {
            const f4 ga = ((const f4*)s_feat[j])[0];
            const f4 gb = ((const f4*)s_feat[j])[1];
            float dot = fa.x * ga.x + fa.y * ga.y + fa.z * ga.z + fa.w * ga.w
                      + fb.x * gb.x + fb.y * gb.y + fb.z * gb.z + fb.w * gb.w;
            // ties -> lower index (jax.lax.top_k), reproduced by strict <
            float dist = ni + s_norm[j] - 2.f * dot;
            if (dist < v2) {
                v2 = dist; i2 = j;
                if (v2 < v1) {
                    float tv = v1; v1 = v2; v2 = tv; int ti = i1; i1 = i2; i2 = ti;
                    if (v1 < v0) {
                        tv = v0; v0 = v1; v1 = tv; ti = i0; i0 = i1; i1 = ti;
                    }
                }
            }
        }
        s_idx[t][0] = i0; s_idx[t][1] = i1; s_idx[t][2] = i2;
        int dk0 = i0 - t, dk1 = i1 - t, dk2 = i2 - t;
        s_near[t][0] = (dk0 < TTH && dk0 > -TTH);
        s_near[t][1] = (dk1 < TTH && dk1 > -TTH);
        s_near[t][2] = (dk2 < TTH && dk2 > -TTH);
    } else {
        for (int i = t - TD; i < 2880; i += 96) s_pool[i] = 0.f;
        for (int i = t - TD; i < TD;   i += 96) { s_degP[i] = 0; s_degN[i] = 0; }
    }
    __syncthreads();

    // ---------- phase 3: h = leaky_relu(feature @ f1w^T + f1b) ----------
    for (int task = t; task < TD * TG; task += 256) {
        const int d = task >> 3, go = task & 7;
        float s = s_f1b[go];
#pragma unroll
        for (int gi = 0; gi < TG; ++gi) s = fmaf(s_feat[d][gi], s_f1w[go * TG + gi], s);
        s_h[d * 9 + go] = (s >= 0.f) ? s : 0.01f * s;
    }
    __syncthreads();

    // ---------- phase 4/5: E = mean(h over near/far kNN), scatter ----------
    if (t < TD) {
        const int jj[3] = { s_idx[t][0], s_idx[t][1], s_idx[t][2] };
        const int nr[3] = { s_near[t][0], s_near[t][1], s_near[t][2] };
        float ep[TG] = {0, 0, 0, 0, 0, 0, 0, 0};
        float en[TG] = {0, 0, 0, 0, 0, 0, 0, 0};
        int cp = 0, cn = 0;
#pragma unroll
        for (int k = 0; k < TK; ++k) {
            const float* hp = &s_h[jj[k] * 9];
            if (nr[k]) { cp++;
#pragma unroll
                for (int g = 0; g < TG; ++g) ep[g] += hp[g];
            } else { cn++;
#pragma unroll
                for (int g = 0; g < TG; ++g) en[g] += hp[g];
            }
        }
        if (cp) {
#pragma unroll
            for (int g = 0; g < TG; ++g) ep[g] /= (float)cp;
        }
        if (cn) {
#pragma unroll
            for (int g = 0; g < TG; ++g) en[g] /= (float)cn;
        }
#pragma unroll
        for (int k = 0; k < TK; ++k) {
            if (nr[k]) {
                atomicAdd(&s_degP[jj[k]], 1);
#pragma unroll
                for (int g = 0; g < TG; ++g) atomicAdd(&s_accP[jj[k] * 9 + g], ep[g]);
            } else {
                atomicAdd(&s_degN[jj[k]], 1);
#pragma unroll
                for (int g = 0; g < TG; ++g) atomicAdd(&s_accN[jj[k] * 9 + g], en[g]);
            }
        }
    }
    __syncthreads();

    // ---------- phase 5b: feat' = feature + 0.1*x1 - 0.1*x2 ----------
    if (t < TD) {
        const int dp = s_degP[t], dn = s_degN[t];
#pragma unroll
        for (int g = 0; g < TG; ++g) {
            float x1 = dp ? s_accP[t * 9 + g] / (float)dp : 0.f;
            float x2 = dn ? s_accN[t * 9 + g] / (float)dn : 0.f;
            s_accP[t * 9 + g] = s_feat[t][g] + 0.1f * x1 - 0.1f * x2;
        }
    }
    __syncthreads();

    // ---------- phase 6: conv1d(k=3,pad=1) over D + mask ----------
    if (t < TD) {
        float msum = 0.f;
#pragma unroll
        for (int g = 0; g < TG; ++g) msum += s_feat[t][g];
        float a = s_cb;
#pragma unroll
        for (int kw = 0; kw < 3; ++kw) {
            const int dd = t + kw - 1;
            if (dd >= 0 && dd < TD) {
#pragma unroll
                for (int g = 0; g < TG; ++g)
                    a = fmaf(s_accP[dd * 9 + g], s_cw[g * 3 + kw], a);
            }
        }
        s_agg[t] = (msum == 0.f) ? NEGV : a;
    }
    __syncthreads();

    // ---------- phase 7: softmax + disparity regression (wave 0) ----------
    if (t < 64) {
        float m = -3e38f;
        for (int d = t; d < TD; d += 64) m = fmaxf(m, s_agg[d]);
#pragma unroll
        for (int off = 32; off; off >>= 1) m = fmaxf(m, __shfl_xor(m, off, 64));
        float se = 0.f, sd = 0.f;
        for (int d = t; d < TD; d += 64) {
            float e = expf(s_agg[d] - m);
            se += e;
            sd = fmaf(e, (float)d, sd);
        }
#pragma unroll
        for (int off = 32; off; off >>= 1) {
            se += __shfl_xor(se, off, 64);
            sd += __shfl_xor(sd, off, 64);
        }
        if (t == 0) out[bn] = sd / se;
    }
}

extern "C" void kernel_launch(void* const* d_in, const int* in_sizes, int n_in,
                              void* d_out, int out_size, void* d_ws, size_t ws_size,
                              hipStream_t stream) {
    const float* left   = (const float*)d_in[0];
    const float* right  = (const float*)d_in[1];
    const int*   start  = (const int*)d_in[2];
    const float* f1w    = (const float*)d_in[3];
    const float* f1b    = (const float*)d_in[4];
    const float* convw  = (const float*)d_in[5];
    const float* convb  = (const float*)d_in[6];
    float* out = (float*)d_out;
    patchmix_kernel<<<TBN, 256, 0, stream>>>(left, right, start, f1w, f1b,
                                             convw, convb, out);
}